// Round 8
// baseline (260.015 us; speedup 1.0000x reference)
//
#include <hip/hip_runtime.h>
#include <hip/hip_bf16.h>
#include <math.h>

#define DIMC 384
#define NH 6
#define HD 64
#define MLPD 1536
#define BS 8
#define SEQ 1024
#define T_TOK (BS*SEQ)                  // 8192 tokens
#define TC ((size_t)T_TOK*DIMC)         // 3,145,728 elems
#define QK_SCALE 0.125f                 // 64^-0.5

typedef __bf16 bf16;
typedef bf16 bf16x4 __attribute__((ext_vector_type(4)));
typedef bf16 bf16x8 __attribute__((ext_vector_type(8)));
typedef float floatx4 __attribute__((ext_vector_type(4)));

// async global->LDS 16B (per-lane LDS dest must equal wave-uniform-base + lane*16)
__device__ __forceinline__ void async_cp16(const void* gsrc, void* ldst) {
    __builtin_amdgcn_global_load_lds(
        (const __attribute__((address_space(1))) unsigned int*)gsrc,
        (__attribute__((address_space(3))) unsigned int*)ldst,
        16, 0, 0);
}

// ---------- fp32 -> bf16 weight conversion (qkv_w | proj_w | w1 | w2 contiguous) ----------
__global__ __launch_bounds__(256)
void cvt_all(const float* __restrict__ s0, const float* __restrict__ s1,
             const float* __restrict__ s2, const float* __restrict__ s3,
             bf16* __restrict__ dst) {
    int i = blockIdx.x * 256 + threadIdx.x;   // i < 442368 float4 chunks
    const int n0 = 110592, n1 = 36864, n2 = 147456;   // float4 counts
    const float4* src; int j;
    if (i < n0)           { src = (const float4*)s0; j = i; }
    else if (i < n0+n1)   { src = (const float4*)s1; j = i - n0; }
    else if (i < n0+n1+n2){ src = (const float4*)s2; j = i - n0 - n1; }
    else                  { src = (const float4*)s3; j = i - n0 - n1 - n2; }
    float4 v = src[j];
    bf16x4 o; o[0] = (bf16)v.x; o[1] = (bf16)v.y; o[2] = (bf16)v.z; o[3] = (bf16)v.w;
    ((bf16x4*)dst)[i] = o;
}

// ---------------- LayerNorm: 256 thr = 4 rows (1 wave/row), fp32 in, bf16 out ----------
__global__ __launch_bounds__(256)
void ln_kernel(const float* __restrict__ x, const float* __restrict__ w,
               const float* __restrict__ b, bf16* __restrict__ out) {
    int row = blockIdx.x * 4 + (threadIdx.x >> 6);
    int t = threadIdx.x & 63;
    const float* xr = x + (size_t)row * DIMC;
    float vals[6];
    float s = 0.f;
    #pragma unroll
    for (int i = 0; i < 6; i++) { vals[i] = xr[t + i*64]; s += vals[i]; }
    #pragma unroll
    for (int m = 32; m; m >>= 1) s += __shfl_xor(s, m);
    float mean = s * (1.0f / DIMC);
    float sq = 0.f;
    #pragma unroll
    for (int i = 0; i < 6; i++) { float d = vals[i] - mean; sq += d * d; }
    #pragma unroll
    for (int m = 32; m; m >>= 1) sq += __shfl_xor(sq, m);
    float rstd = rsqrtf(sq * (1.0f / DIMC) + 1e-5f);
    bf16* orow = out + (size_t)row * DIMC;
    #pragma unroll
    for (int i = 0; i < 6; i++) {
        int c = t + i*64;
        orow[c] = (bf16)((vals[i] - mean) * rstd * w[c] + b[c]);
    }
}

// ---- fused: x1 = x + Pp0 + Pp1 + proj_b (write fp32 x1) ; h = LN2(x1) (write bf16) ----
__global__ __launch_bounds__(256)
void ln2_fused(const float* __restrict__ x, const bf16* __restrict__ p0,
               const bf16* __restrict__ p1, const float* __restrict__ pb,
               const float* __restrict__ w, const float* __restrict__ b,
               float* __restrict__ x1, bf16* __restrict__ h) {
    int row = blockIdx.x * 4 + (threadIdx.x >> 6);
    int t = threadIdx.x & 63;
    size_t base = (size_t)row * DIMC;
    float vals[6];
    float s = 0.f;
    #pragma unroll
    for (int i = 0; i < 6; i++) {
        int c = t + i*64;
        float v = x[base + c] + (float)p0[base + c] + (float)p1[base + c] + pb[c];
        vals[i] = v; s += v;
    }
    #pragma unroll
    for (int m = 32; m; m >>= 1) s += __shfl_xor(s, m);
    float mean = s * (1.0f / DIMC);
    float sq = 0.f;
    #pragma unroll
    for (int i = 0; i < 6; i++) { float d = vals[i] - mean; sq += d * d; }
    #pragma unroll
    for (int m = 32; m; m >>= 1) sq += __shfl_xor(sq, m);
    float rstd = rsqrtf(sq * (1.0f / DIMC) + 1e-5f);
    #pragma unroll
    for (int i = 0; i < 6; i++) {
        int c = t + i*64;
        x1[base + c] = vals[i];
        h[base + c] = (bf16)((vals[i] - mean) * rstd * w[c] + b[c]);
    }
}

// ---- final: out = x1 + b2 + Pm0+Pm1+Pm2+Pm3 (bf16 partials), float4-vectorized ----
__global__ __launch_bounds__(256)
void reduce4(float* __restrict__ xo, const bf16* __restrict__ p0, const bf16* __restrict__ p1,
             const bf16* __restrict__ p2, const bf16* __restrict__ p3,
             const float* __restrict__ b2) {
    int i = blockIdx.x * 256 + threadIdx.x;   // float4 index, < TC/4
    float4 v = ((const float4*)xo)[i];
    int c = (i % 96) * 4;
    float4 bb = *(const float4*)(b2 + c);
    bf16x4 a0 = ((const bf16x4*)p0)[i], a1 = ((const bf16x4*)p1)[i];
    bf16x4 a2 = ((const bf16x4*)p2)[i], a3 = ((const bf16x4*)p3)[i];
    v.x += bb.x + (float)a0[0] + (float)a1[0] + (float)a2[0] + (float)a3[0];
    v.y += bb.y + (float)a0[1] + (float)a1[1] + (float)a2[1] + (float)a3[1];
    v.z += bb.z + (float)a0[2] + (float)a1[2] + (float)a2[2] + (float)a3[2];
    v.w += bb.w + (float)a0[3] + (float)a1[3] + (float)a2[3] + (float)a3[3];
    ((float4*)xo)[i] = v;
}

// ---------------- GEMM: C[M,N] = A[M,K] @ W[N,K]^T, m97-style SINGLE-buffer staging ------
// (r4 version restored: 32KB LDS -> 3-5 blocks/CU; dbuf's 64KB = 2 blocks/CU regressed,
//  matching the m132 precedent.)
enum { EPI_NONE = 0, EPI_QKV = 1, EPI_GELU = 3 };

template<int EPI, int K, int KS, typename OutT>
__global__ __launch_bounds__(256)
void gemm_bt(const bf16* __restrict__ A, const bf16* __restrict__ W,
             const float* __restrict__ bias, OutT* out, int M, int N) {
    __shared__ __align__(16) bf16 Ash[128*32];
    __shared__ __align__(16) bf16 Bsh[128*32];
    constexpr int KB = K / KS;               // K extent per block
    int tid = threadIdx.x;
    int lane = tid & 63, w = tid >> 6;
    int quad = lane >> 4, l16 = lane & 15;
    int rbase = blockIdx.y * 128 + (w >> 1) * 64;
    int cbase = blockIdx.x * 128 + (w & 1) * 64;
    int kbase = blockIdx.z * KB;
    int c1 = w * 64 + lane;                  // [0,256)
    int c2 = c1 + 256;                       // [256,512)
    const bf16* Ag1 = A + (size_t)(blockIdx.y*128 + (c1 >> 2)) * K + kbase + (c1 & 3) * 8;
    const bf16* Ag2 = A + (size_t)(blockIdx.y*128 + (c2 >> 2)) * K + kbase + (c2 & 3) * 8;
    const bf16* Wg1 = W + (size_t)(blockIdx.x*128 + (c1 >> 2)) * K + kbase + (c1 & 3) * 8;
    const bf16* Wg2 = W + (size_t)(blockIdx.x*128 + (c2 >> 2)) * K + kbase + (c2 & 3) * 8;
    bf16* As1 = Ash + c1 * 8;  bf16* As2 = Ash + c2 * 8;
    bf16* Bs1 = Bsh + c1 * 8;  bf16* Bs2 = Bsh + c2 * 8;

    int arow = (w >> 1) * 64;
    int brow = (w & 1) * 64;
    floatx4 acc[4][4] = {};
    #pragma unroll
    for (int kk = 0; kk < KB / 32; kk++) {
        __syncthreads();
        async_cp16(Ag1 + kk*32, As1);
        async_cp16(Ag2 + kk*32, As2);
        async_cp16(Wg1 + kk*32, Bs1);
        async_cp16(Wg2 + kk*32, Bs2);
        __syncthreads();
        bf16x8 a[4], bfr[4];
        #pragma unroll
        for (int tm = 0; tm < 4; tm++)
            a[tm] = *(const bf16x8*)&Ash[(arow + tm*16 + l16) * 32 + quad*8];
        #pragma unroll
        for (int tn = 0; tn < 4; tn++)
            bfr[tn] = *(const bf16x8*)&Bsh[(brow + tn*16 + l16) * 32 + quad*8];
        #pragma unroll
        for (int tm = 0; tm < 4; tm++)
            #pragma unroll
            for (int tn = 0; tn < 4; tn++)
                acc[tm][tn] = __builtin_amdgcn_mfma_f32_16x16x32_bf16(a[tm], bfr[tn], acc[tm][tn], 0, 0, 0);
    }

    #pragma unroll
    for (int tm = 0; tm < 4; tm++)
        #pragma unroll
        for (int tn = 0; tn < 4; tn++) {
            if constexpr (EPI == EPI_QKV) {
                int colb = cbase + tn*16 + l16;       // uniform 'which' per tile (384%16==0)
                int which = colb / 384;
                int rowb = rbase + tm*16 + quad*4;
                int bb = rowb >> 10;
                if (which == 2) {
                    int rem = colb - 768;
                    int hh = rem >> 6, d = rem & 63;
                    int n = rowb & 1023;
                    bf16x4 pk;
                    #pragma unroll
                    for (int r = 0; r < 4; r++) pk[r] = (bf16)acc[tm][tn][r];
                    *(bf16x4*)((bf16*)out + 2*TC + (((size_t)(bb*NH + hh) * HD + d) << 10) + n) = pk;
                } else {
                    int rem = colb - which*384;
                    int hh = rem >> 6, d = rem & 63;
                    #pragma unroll
                    for (int r = 0; r < 4; r++) {
                        int n = (rowb & 1023) + r;
                        ((bf16*)out)[(size_t)which*TC + (((size_t)(bb*NH + hh) * SEQ + n) << 6) + d]
                            = (bf16)acc[tm][tn][r];
                    }
                }
            } else if constexpr (EPI == EPI_NONE) {
                OutT* ob = out + (size_t)blockIdx.z * M * N;
                #pragma unroll
                for (int r = 0; r < 4; r++) {
                    int row = rbase + tm*16 + quad*4 + r;
                    int col = cbase + tn*16 + l16;
                    ob[(size_t)row * N + col] = (OutT)acc[tm][tn][r];
                }
            } else {  // EPI_GELU
                #pragma unroll
                for (int r = 0; r < 4; r++) {
                    int row = rbase + tm*16 + quad*4 + r;
                    int col = cbase + tn*16 + l16;
                    float v = acc[tm][tn][r] + bias[col];
                    v = 0.5f * v * (1.0f + erff(v * 0.70710678118f));
                    out[(size_t)row * N + col] = (OutT)v;
                }
            }
        }
}

// ---------------- Fused L2Q attention, split-K across 4 waves ----------------
// r5 structure + compile-time-unrolled kt loop with V-loads hoisted beside K-loads
// (16 independent global loads issued up front; V latency hides under S-MFMA+poly).
// __launch_bounds__(256,3) caps VGPR ~170 so hoisting can't drop occupancy below
// 3 waves/SIMD (the r6 failure mode).
__global__ __launch_bounds__(256, 3)
void attn_kernel(const bf16* __restrict__ q, const bf16* __restrict__ k,
                 const bf16* __restrict__ vt, const float* __restrict__ alpha,
                 const float* __restrict__ beta, const float* __restrict__ gamma,
                 bf16* __restrict__ attn_out) {
    __shared__ __align__(16) char smem[52992];
    bf16  (*Psh)[72] = (bf16(*)[72])smem;       // [4*64][72] wave-private P tiles
    float (*Ored)[68] = (float(*)[68])smem;     // [3*64][68] overlay (after loop)
    float* rsred = (float*)(smem + 52224);      // [3*64]

    int L = blockIdx.x;
    int xcd = L & 7, slot = L >> 3;
    int qt = slot & 15;
    int bh = xcd + ((slot >> 4) << 3);          // {xcd, xcd+8, ..., xcd+40}
    int bb = bh / NH, h = bh % NH;
    int q0 = qt * 64;
    int tid = threadIdx.x;
    int w = tid >> 6, lane = tid & 63, quad = lane >> 4, l16 = lane & 15;
    float av = alpha[h] * (QK_SCALE * QK_SCALE), bv = beta[h] * QK_SCALE, gv = gamma[h];
    const bf16* qb  = q  + (size_t)bh * SEQ * HD;
    const bf16* kb  = k  + (size_t)bh * SEQ * HD;
    const bf16* vtb = vt + (size_t)bh * HD * SEQ;

    bf16x8 qa[4][2];
    #pragma unroll
    for (int tm = 0; tm < 4; tm++)
        #pragma unroll
        for (int ks = 0; ks < 2; ks++)
            qa[tm][ks] = *(const bf16x8*)(qb + (size_t)(q0 + tm*16 + l16) * HD + ks*32 + quad*8);

    bf16x8 vone;
    #pragma unroll
    for (int j = 0; j < 8; j++) vone[j] = (bf16)1.0f;

    floatx4 o[4][4] = {};
    floatx4 rsacc[4] = {};
    int prow = w * 64;
    int rd_sw = ((l16 >> 2) & 3) << 3;

    #pragma unroll
    for (int i = 0; i < 4; i++) {
        int kb0 = (w*4 + i) * 64;
        // all 16 independent loads up front: 8 K-frags + 8 V-frags
        bf16x8 kf[2][4], vf[2][4];
        #pragma unroll
        for (int ks = 0; ks < 2; ks++)
            #pragma unroll
            for (int tn = 0; tn < 4; tn++) {
                kf[ks][tn] = *(const bf16x8*)(kb + (size_t)(kb0 + tn*16 + l16) * HD + ks*32 + quad*8);
                vf[ks][tn] = *(const bf16x8*)(vtb + (size_t)(tn*16 + l16) * SEQ + kb0 + ks*32 + quad*8);
            }
        #pragma unroll
        for (int tm = 0; tm < 4; tm++) {
            floatx4 s[4] = {};
            #pragma unroll
            for (int ks = 0; ks < 2; ks++)
                #pragma unroll
                for (int tn = 0; tn < 4; tn++)
                    s[tn] = __builtin_amdgcn_mfma_f32_16x16x32_bf16(qa[tm][ks], kf[ks][tn], s[tn], 0, 0, 0);
            #pragma unroll
            for (int tn = 0; tn < 4; tn++)
                #pragma unroll
                for (int r = 0; r < 4; r++) {
                    float xx = s[tn][r];
                    float p = fmaxf((av*xx + bv)*xx + gv, 0.f);
                    int row = tm*16 + quad*4 + r;
                    int col = (tn*16 + l16) ^ (quad << 3);   // bank swizzle
                    Psh[prow + row][col] = (bf16)p;
                }
        }
        #pragma unroll
        for (int ks = 0; ks < 2; ks++) {
            bf16x8 pf[4];
            #pragma unroll
            for (int tm = 0; tm < 4; tm++)
                pf[tm] = *(const bf16x8*)&Psh[prow + tm*16 + l16][(ks*32 + quad*8) ^ rd_sw];
            #pragma unroll
            for (int tm = 0; tm < 4; tm++)
                rsacc[tm] = __builtin_amdgcn_mfma_f32_16x16x32_bf16(pf[tm], vone, rsacc[tm], 0, 0, 0);
            #pragma unroll
            for (int tm = 0; tm < 4; tm++)
                #pragma unroll
                for (int tn = 0; tn < 4; tn++)
                    o[tm][tn] = __builtin_amdgcn_mfma_f32_16x16x32_bf16(pf[tm], vf[ks][tn], o[tm][tn], 0, 0, 0);
        }
    }

    __syncthreads();                       // all P reads done -> safe to overlay
    if (w) {
        #pragma unroll
        for (int tm = 0; tm < 4; tm++) {
            #pragma unroll
            for (int tn = 0; tn < 4; tn++)
                #pragma unroll
                for (int r = 0; r < 4; r++)
                    Ored[(w-1)*64 + tm*16 + quad*4 + r][tn*16 + l16] = o[tm][tn][r];
            if (l16 == 0)
                #pragma unroll
                for (int r = 0; r < 4; r++)
                    rsred[(w-1)*64 + tm*16 + quad*4 + r] = rsacc[tm][r];
        }
    }
    __syncthreads();
    if (w == 0) {
        #pragma unroll
        for (int j = 0; j < 3; j++)
            #pragma unroll
            for (int tm = 0; tm < 4; tm++) {
                #pragma unroll
                for (int tn = 0; tn < 4; tn++)
                    #pragma unroll
                    for (int r = 0; r < 4; r++)
                        o[tm][tn][r] += Ored[j*64 + tm*16 + quad*4 + r][tn*16 + l16];
                #pragma unroll
                for (int r = 0; r < 4; r++)
                    rsacc[tm][r] += rsred[j*64 + tm*16 + quad*4 + r];
            }
        #pragma unroll
        for (int tm = 0; tm < 4; tm++)
            #pragma unroll
            for (int tn = 0; tn < 4; tn++)
                #pragma unroll
                for (int r = 0; r < 4; r++) {
                    int n = q0 + tm*16 + quad*4 + r;
                    attn_out[((size_t)(bb*SEQ + n)) * DIMC + h*HD + tn*16 + l16] =
                        (bf16)(o[tm][tn][r] / (rsacc[tm][r] + 1e-6f));
                }
    }
}

// ---------------- driver ----------------
extern "C" void kernel_launch(void* const* d_in, const int* in_sizes, int n_in,
                              void* d_out, int out_size, void* d_ws, size_t ws_size,
                              hipStream_t stream) {
    const float* x      = (const float*)d_in[0];
    const float* qkv_w  = (const float*)d_in[1];
    const float* proj_w = (const float*)d_in[2];
    const float* proj_b = (const float*)d_in[3];
    const float* alpha  = (const float*)d_in[4];
    const float* beta   = (const float*)d_in[5];
    const float* gamma  = (const float*)d_in[6];
    const float* ln1_w  = (const float*)d_in[7];
    const float* ln1_b  = (const float*)d_in[8];
    const float* ln2_w  = (const float*)d_in[9];
    const float* ln2_b  = (const float*)d_in[10];
    const float* w1     = (const float*)d_in[11];
    const float* b1     = (const float*)d_in[12];
    const float* w2     = (const float*)d_in[13];
    const float* b2     = (const float*)d_in[14];
    float* out = (float*)d_out;           // fp32 output; also doubles as x1 buffer

    char* base = (char*)d_ws;
    bf16* wq_bf = (bf16*)base;                 // 1152x384
    bf16* wp_bf = wq_bf + 442368;              // 384x384
    bf16* w1_bf = wq_bf + 589824;              // 1536x384
    bf16* w2_bf = wq_bf + 1179648;             // 384x1536
    bf16* h      = (bf16*)(base + 3538944);
    bf16* qkv    = (bf16*)(base + 9830400);
    bf16* attn_o = (bf16*)(base + 28704768);
    bf16* m      = qkv;                        // overlays qkv+attn_o (both dead by mlp1)
    bf16* Pp     = (bf16*)(base + 34996224);   // 2*TC (proj split-K partials)
    bf16* Pm     = (bf16*)(base + 34996224);   // 4*TC (mlp2 split-K partials; Pp dead)

    cvt_all<<<1728, 256, 0, stream>>>(qkv_w, proj_w, w1, w2, wq_bf);
    ln_kernel<<<T_TOK/4, 256, 0, stream>>>(x, ln1_w, ln1_b, h);
    gemm_bt<EPI_QKV, 384, 1, bf16><<<dim3(9, 64, 1), 256, 0, stream>>>(
        h, wq_bf, nullptr, qkv, T_TOK, 1152);
    attn_kernel<<<768, 256, 0, stream>>>(
        qkv, qkv + TC, qkv + 2*TC, alpha, beta, gamma, attn_o);
    gemm_bt<EPI_NONE, 384, 2, bf16><<<dim3(3, 64, 2), 256, 0, stream>>>(
        attn_o, wp_bf, nullptr, Pp, T_TOK, DIMC);
    ln2_fused<<<T_TOK/4, 256, 0, stream>>>(x, Pp, Pp + TC, proj_b, ln2_w, ln2_b, out, h);
    gemm_bt<EPI_GELU, 384, 1, bf16><<<dim3(12, 64, 1), 256, 0, stream>>>(
        h, w1_bf, b1, m, T_TOK, MLPD);
    gemm_bt<EPI_NONE, 1536, 4, bf16><<<dim3(3, 64, 4), 256, 0, stream>>>(
        m, w2_bf, nullptr, Pm, T_TOK, DIMC);
    reduce4<<<TC/4/256, 256, 0, stream>>>(out, Pm, Pm + TC, Pm + 2*TC, Pm + 3*TC, b2);
}

// Round 9
// 245.949 us; speedup vs baseline: 1.0572x; 1.0572x over previous
//
#include <hip/hip_runtime.h>
#include <hip/hip_bf16.h>
#include <math.h>

#define DIMC 384
#define NH 6
#define HD 64
#define MLPD 1536
#define BS 8
#define SEQ 1024
#define T_TOK (BS*SEQ)                  // 8192 tokens
#define TC ((size_t)T_TOK*DIMC)         // 3,145,728 elems
#define QK_SCALE 0.125f                 // 64^-0.5

typedef __bf16 bf16;
typedef bf16 bf16x4 __attribute__((ext_vector_type(4)));
typedef bf16 bf16x8 __attribute__((ext_vector_type(8)));
typedef float floatx4 __attribute__((ext_vector_type(4)));

// async global->LDS 16B (per-lane LDS dest must equal wave-uniform-base + lane*16)
__device__ __forceinline__ void async_cp16(const void* gsrc, void* ldst) {
    __builtin_amdgcn_global_load_lds(
        (const __attribute__((address_space(1))) unsigned int*)gsrc,
        (__attribute__((address_space(3))) unsigned int*)ldst,
        16, 0, 0);
}

// ---------- fp32 -> bf16 weight conversion (qkv_w | proj_w | w1 | w2 contiguous) ----------
__global__ __launch_bounds__(256)
void cvt_all(const float* __restrict__ s0, const float* __restrict__ s1,
             const float* __restrict__ s2, const float* __restrict__ s3,
             bf16* __restrict__ dst) {
    int i = blockIdx.x * 256 + threadIdx.x;   // i < 442368 float4 chunks
    const int n0 = 110592, n1 = 36864, n2 = 147456;   // float4 counts
    const float4* src; int j;
    if (i < n0)           { src = (const float4*)s0; j = i; }
    else if (i < n0+n1)   { src = (const float4*)s1; j = i - n0; }
    else if (i < n0+n1+n2){ src = (const float4*)s2; j = i - n0 - n1; }
    else                  { src = (const float4*)s3; j = i - n0 - n1 - n2; }
    float4 v = src[j];
    bf16x4 o; o[0] = (bf16)v.x; o[1] = (bf16)v.y; o[2] = (bf16)v.z; o[3] = (bf16)v.w;
    ((bf16x4*)dst)[i] = o;
}

// ---------------- LayerNorm: 256 thr = 4 rows (1 wave/row), fp32 in, bf16 out ----------
__global__ __launch_bounds__(256)
void ln_kernel(const float* __restrict__ x, const float* __restrict__ w,
               const float* __restrict__ b, bf16* __restrict__ out) {
    int row = blockIdx.x * 4 + (threadIdx.x >> 6);
    int t = threadIdx.x & 63;
    const float* xr = x + (size_t)row * DIMC;
    float vals[6];
    float s = 0.f;
    #pragma unroll
    for (int i = 0; i < 6; i++) { vals[i] = xr[t + i*64]; s += vals[i]; }
    #pragma unroll
    for (int m = 32; m; m >>= 1) s += __shfl_xor(s, m);
    float mean = s * (1.0f / DIMC);
    float sq = 0.f;
    #pragma unroll
    for (int i = 0; i < 6; i++) { float d = vals[i] - mean; sq += d * d; }
    #pragma unroll
    for (int m = 32; m; m >>= 1) sq += __shfl_xor(sq, m);
    float rstd = rsqrtf(sq * (1.0f / DIMC) + 1e-5f);
    bf16* orow = out + (size_t)row * DIMC;
    #pragma unroll
    for (int i = 0; i < 6; i++) {
        int c = t + i*64;
        orow[c] = (bf16)((vals[i] - mean) * rstd * w[c] + b[c]);
    }
}

// ---- fused: x1 = x + Pp0 + Pp1 + proj_b (write fp32 x1) ; h = LN2(x1) (write bf16) ----
__global__ __launch_bounds__(256)
void ln2_fused(const float* __restrict__ x, const bf16* __restrict__ p0,
               const bf16* __restrict__ p1, const float* __restrict__ pb,
               const float* __restrict__ w, const float* __restrict__ b,
               float* __restrict__ x1, bf16* __restrict__ h) {
    int row = blockIdx.x * 4 + (threadIdx.x >> 6);
    int t = threadIdx.x & 63;
    size_t base = (size_t)row * DIMC;
    float vals[6];
    float s = 0.f;
    #pragma unroll
    for (int i = 0; i < 6; i++) {
        int c = t + i*64;
        float v = x[base + c] + (float)p0[base + c] + (float)p1[base + c] + pb[c];
        vals[i] = v; s += v;
    }
    #pragma unroll
    for (int m = 32; m; m >>= 1) s += __shfl_xor(s, m);
    float mean = s * (1.0f / DIMC);
    float sq = 0.f;
    #pragma unroll
    for (int i = 0; i < 6; i++) { float d = vals[i] - mean; sq += d * d; }
    #pragma unroll
    for (int m = 32; m; m >>= 1) sq += __shfl_xor(sq, m);
    float rstd = rsqrtf(sq * (1.0f / DIMC) + 1e-5f);
    #pragma unroll
    for (int i = 0; i < 6; i++) {
        int c = t + i*64;
        x1[base + c] = vals[i];
        h[base + c] = (bf16)((vals[i] - mean) * rstd * w[c] + b[c]);
    }
}

// ---- final: out = x1 + b2 + Pm0+Pm1+Pm2+Pm3 (bf16 partials), float4-vectorized ----
__global__ __launch_bounds__(256)
void reduce4(float* __restrict__ xo, const bf16* __restrict__ p0, const bf16* __restrict__ p1,
             const bf16* __restrict__ p2, const bf16* __restrict__ p3,
             const float* __restrict__ b2) {
    int i = blockIdx.x * 256 + threadIdx.x;   // float4 index, < TC/4
    float4 v = ((const float4*)xo)[i];
    int c = (i % 96) * 4;
    float4 bb = *(const float4*)(b2 + c);
    bf16x4 a0 = ((const bf16x4*)p0)[i], a1 = ((const bf16x4*)p1)[i];
    bf16x4 a2 = ((const bf16x4*)p2)[i], a3 = ((const bf16x4*)p3)[i];
    v.x += bb.x + (float)a0[0] + (float)a1[0] + (float)a2[0] + (float)a3[0];
    v.y += bb.y + (float)a0[1] + (float)a1[1] + (float)a2[1] + (float)a3[1];
    v.z += bb.z + (float)a0[2] + (float)a1[2] + (float)a2[2] + (float)a3[2];
    v.w += bb.w + (float)a0[3] + (float)a1[3] + (float)a2[3] + (float)a3[3];
    ((float4*)xo)[i] = v;
}

// ---------------- GEMM: C[M,N] = A[M,K] @ W[N,K]^T, DOUBLE-BUFFERED LDS staging --------
// (r7 version restored: r7's apparent regression was a throttled machine state — normalized
//  by the attention clock-anchor, dbuf was a ~50 us win. LDS 32KB/block, no occupancy cliff.)
// Preload tile 0; each iter: sync (drains the DMA that has had a full compute phase in
// flight), fire DMA for tile k+1 into the other buffer, compute tile k.
enum { EPI_NONE = 0, EPI_QKV = 1, EPI_GELU = 3 };

template<int EPI, int K, int KS, typename OutT>
__global__ __launch_bounds__(256)
void gemm_bt(const bf16* __restrict__ A, const bf16* __restrict__ W,
             const float* __restrict__ bias, OutT* out, int M, int N) {
    __shared__ __align__(16) bf16 Ash[2][128*32];
    __shared__ __align__(16) bf16 Bsh[2][128*32];
    constexpr int KB = K / KS;               // K extent per block
    constexpr int NI = KB / 32;              // iterations
    int tid = threadIdx.x;
    int lane = tid & 63, w = tid >> 6;
    int quad = lane >> 4, l16 = lane & 15;
    int rbase = blockIdx.y * 128 + (w >> 1) * 64;
    int cbase = blockIdx.x * 128 + (w & 1) * 64;
    int kbase = blockIdx.z * KB;
    int c1 = w * 64 + lane;                  // [0,256)
    int c2 = c1 + 256;                       // [256,512)
    const bf16* Ag1 = A + (size_t)(blockIdx.y*128 + (c1 >> 2)) * K + kbase + (c1 & 3) * 8;
    const bf16* Ag2 = A + (size_t)(blockIdx.y*128 + (c2 >> 2)) * K + kbase + (c2 & 3) * 8;
    const bf16* Wg1 = W + (size_t)(blockIdx.x*128 + (c1 >> 2)) * K + kbase + (c1 & 3) * 8;
    const bf16* Wg2 = W + (size_t)(blockIdx.x*128 + (c2 >> 2)) * K + kbase + (c2 & 3) * 8;
    int off1 = c1 * 8, off2 = c2 * 8;

    int arow = (w >> 1) * 64;
    int brow = (w & 1) * 64;
    floatx4 acc[4][4] = {};

    // preload tile 0 into buffer 0
    async_cp16(Ag1, Ash[0] + off1);
    async_cp16(Ag2, Ash[0] + off2);
    async_cp16(Wg1, Bsh[0] + off1);
    async_cp16(Wg2, Bsh[0] + off2);

    #pragma unroll
    for (int kk = 0; kk < NI; kk++) {
        __syncthreads();                     // drains buf[kk&1] DMA; readers of buf[(kk+1)&1] done
        if (kk + 1 < NI) {
            async_cp16(Ag1 + (kk+1)*32, Ash[(kk+1)&1] + off1);
            async_cp16(Ag2 + (kk+1)*32, Ash[(kk+1)&1] + off2);
            async_cp16(Wg1 + (kk+1)*32, Bsh[(kk+1)&1] + off1);
            async_cp16(Wg2 + (kk+1)*32, Bsh[(kk+1)&1] + off2);
        }
        const bf16* As = Ash[kk & 1];
        const bf16* Bs = Bsh[kk & 1];
        bf16x8 a[4], bfr[4];
        #pragma unroll
        for (int tm = 0; tm < 4; tm++)
            a[tm] = *(const bf16x8*)&As[(arow + tm*16 + l16) * 32 + quad*8];
        #pragma unroll
        for (int tn = 0; tn < 4; tn++)
            bfr[tn] = *(const bf16x8*)&Bs[(brow + tn*16 + l16) * 32 + quad*8];
        #pragma unroll
        for (int tm = 0; tm < 4; tm++)
            #pragma unroll
            for (int tn = 0; tn < 4; tn++)
                acc[tm][tn] = __builtin_amdgcn_mfma_f32_16x16x32_bf16(a[tm], bfr[tn], acc[tm][tn], 0, 0, 0);
    }

    #pragma unroll
    for (int tm = 0; tm < 4; tm++)
        #pragma unroll
        for (int tn = 0; tn < 4; tn++) {
            if constexpr (EPI == EPI_QKV) {
                int colb = cbase + tn*16 + l16;       // uniform 'which' per tile (384%16==0)
                int which = colb / 384;
                int rowb = rbase + tm*16 + quad*4;
                int bb = rowb >> 10;
                if (which == 2) {
                    int rem = colb - 768;
                    int hh = rem >> 6, d = rem & 63;
                    int n = rowb & 1023;
                    bf16x4 pk;
                    #pragma unroll
                    for (int r = 0; r < 4; r++) pk[r] = (bf16)acc[tm][tn][r];
                    *(bf16x4*)((bf16*)out + 2*TC + (((size_t)(bb*NH + hh) * HD + d) << 10) + n) = pk;
                } else {
                    int rem = colb - which*384;
                    int hh = rem >> 6, d = rem & 63;
                    #pragma unroll
                    for (int r = 0; r < 4; r++) {
                        int n = (rowb & 1023) + r;
                        ((bf16*)out)[(size_t)which*TC + (((size_t)(bb*NH + hh) * SEQ + n) << 6) + d]
                            = (bf16)acc[tm][tn][r];
                    }
                }
            } else if constexpr (EPI == EPI_NONE) {
                OutT* ob = out + (size_t)blockIdx.z * M * N;
                #pragma unroll
                for (int r = 0; r < 4; r++) {
                    int row = rbase + tm*16 + quad*4 + r;
                    int col = cbase + tn*16 + l16;
                    ob[(size_t)row * N + col] = (OutT)acc[tm][tn][r];
                }
            } else {  // EPI_GELU
                #pragma unroll
                for (int r = 0; r < 4; r++) {
                    int row = rbase + tm*16 + quad*4 + r;
                    int col = cbase + tn*16 + l16;
                    float v = acc[tm][tn][r] + bias[col];
                    v = 0.5f * v * (1.0f + erff(v * 0.70710678118f));
                    out[(size_t)row * N + col] = (OutT)v;
                }
            }
        }
}

// ---------------- Fused L2Q attention, split-K across 4 waves (r5 verbatim) ----------
// 1-D grid of 768 blocks with XCD-aware decode: xcd = L&7 (round-robin dispatch),
// all 16 q-tiles of a head land on the same XCD -> per-XCD K/V working set 1.5 MB < 4 MB L2.
// NOTE: no __launch_bounds__ min-wave arg (r8's (256,3) caused catastrophic spill),
// no V-hoisting (r6/r8 showed register lifetime stretching backfires here).
__global__ __launch_bounds__(256)
void attn_kernel(const bf16* __restrict__ q, const bf16* __restrict__ k,
                 const bf16* __restrict__ vt, const float* __restrict__ alpha,
                 const float* __restrict__ beta, const float* __restrict__ gamma,
                 bf16* __restrict__ attn_out) {
    __shared__ __align__(16) char smem[52992];
    bf16  (*Psh)[72] = (bf16(*)[72])smem;       // [4*64][72] wave-private P tiles
    float (*Ored)[68] = (float(*)[68])smem;     // [3*64][68] overlay (after loop)
    float* rsred = (float*)(smem + 52224);      // [3*64]

    int L = blockIdx.x;
    int xcd = L & 7, slot = L >> 3;
    int qt = slot & 15;
    int bh = xcd + ((slot >> 4) << 3);          // {xcd, xcd+8, ..., xcd+40}
    int bb = bh / NH, h = bh % NH;
    int q0 = qt * 64;
    int tid = threadIdx.x;
    int w = tid >> 6, lane = tid & 63, quad = lane >> 4, l16 = lane & 15;
    float av = alpha[h] * (QK_SCALE * QK_SCALE), bv = beta[h] * QK_SCALE, gv = gamma[h];
    const bf16* qb  = q  + (size_t)bh * SEQ * HD;
    const bf16* kb  = k  + (size_t)bh * SEQ * HD;
    const bf16* vtb = vt + (size_t)bh * HD * SEQ;

    bf16x8 qa[4][2];
    #pragma unroll
    for (int tm = 0; tm < 4; tm++)
        #pragma unroll
        for (int ks = 0; ks < 2; ks++)
            qa[tm][ks] = *(const bf16x8*)(qb + (size_t)(q0 + tm*16 + l16) * HD + ks*32 + quad*8);

    bf16x8 vone;
    #pragma unroll
    for (int j = 0; j < 8; j++) vone[j] = (bf16)1.0f;

    floatx4 o[4][4] = {};
    floatx4 rsacc[4] = {};
    int prow = w * 64;
    int rd_sw = ((l16 >> 2) & 3) << 3;

    for (int kt = w*4; kt < w*4 + 4; kt++) {
        int kb0 = kt * 64;
        bf16x8 kf[2][4];
        #pragma unroll
        for (int ks = 0; ks < 2; ks++)
            #pragma unroll
            for (int tn = 0; tn < 4; tn++)
                kf[ks][tn] = *(const bf16x8*)(kb + (size_t)(kb0 + tn*16 + l16) * HD + ks*32 + quad*8);
        #pragma unroll
        for (int tm = 0; tm < 4; tm++) {
            floatx4 s[4] = {};
            #pragma unroll
            for (int ks = 0; ks < 2; ks++)
                #pragma unroll
                for (int tn = 0; tn < 4; tn++)
                    s[tn] = __builtin_amdgcn_mfma_f32_16x16x32_bf16(qa[tm][ks], kf[ks][tn], s[tn], 0, 0, 0);
            #pragma unroll
            for (int tn = 0; tn < 4; tn++)
                #pragma unroll
                for (int r = 0; r < 4; r++) {
                    float xx = s[tn][r];
                    float p = fmaxf((av*xx + bv)*xx + gv, 0.f);
                    int row = tm*16 + quad*4 + r;
                    int col = (tn*16 + l16) ^ (quad << 3);   // bank swizzle
                    Psh[prow + row][col] = (bf16)p;
                }
        }
        #pragma unroll
        for (int ks = 0; ks < 2; ks++) {
            bf16x8 vf[4], pf[4];
            #pragma unroll
            for (int tn = 0; tn < 4; tn++)
                vf[tn] = *(const bf16x8*)(vtb + (size_t)(tn*16 + l16) * SEQ + kb0 + ks*32 + quad*8);
            #pragma unroll
            for (int tm = 0; tm < 4; tm++)
                pf[tm] = *(const bf16x8*)&Psh[prow + tm*16 + l16][(ks*32 + quad*8) ^ rd_sw];
            #pragma unroll
            for (int tm = 0; tm < 4; tm++)
                rsacc[tm] = __builtin_amdgcn_mfma_f32_16x16x32_bf16(pf[tm], vone, rsacc[tm], 0, 0, 0);
            #pragma unroll
            for (int tm = 0; tm < 4; tm++)
                #pragma unroll
                for (int tn = 0; tn < 4; tn++)
                    o[tm][tn] = __builtin_amdgcn_mfma_f32_16x16x32_bf16(pf[tm], vf[tn], o[tm][tn], 0, 0, 0);
        }
    }

    __syncthreads();                       // all P reads done -> safe to overlay
    if (w) {
        #pragma unroll
        for (int tm = 0; tm < 4; tm++) {
            #pragma unroll
            for (int tn = 0; tn < 4; tn++)
                #pragma unroll
                for (int r = 0; r < 4; r++)
                    Ored[(w-1)*64 + tm*16 + quad*4 + r][tn*16 + l16] = o[tm][tn][r];
            if (l16 == 0)
                #pragma unroll
                for (int r = 0; r < 4; r++)
                    rsred[(w-1)*64 + tm*16 + quad*4 + r] = rsacc[tm][r];
        }
    }
    __syncthreads();
    if (w == 0) {
        #pragma unroll
        for (int j = 0; j < 3; j++)
            #pragma unroll
            for (int tm = 0; tm < 4; tm++) {
                #pragma unroll
                for (int tn = 0; tn < 4; tn++)
                    #pragma unroll
                    for (int r = 0; r < 4; r++)
                        o[tm][tn][r] += Ored[j*64 + tm*16 + quad*4 + r][tn*16 + l16];
                #pragma unroll
                for (int r = 0; r < 4; r++)
                    rsacc[tm][r] += rsred[j*64 + tm*16 + quad*4 + r];
            }
        #pragma unroll
        for (int tm = 0; tm < 4; tm++)
            #pragma unroll
            for (int tn = 0; tn < 4; tn++)
                #pragma unroll
                for (int r = 0; r < 4; r++) {
                    int n = q0 + tm*16 + quad*4 + r;
                    attn_out[((size_t)(bb*SEQ + n)) * DIMC + h*HD + tn*16 + l16] =
                        (bf16)(o[tm][tn][r] / (rsacc[tm][r] + 1e-6f));
                }
    }
}

// ---------------- driver ----------------
extern "C" void kernel_launch(void* const* d_in, const int* in_sizes, int n_in,
                              void* d_out, int out_size, void* d_ws, size_t ws_size,
                              hipStream_t stream) {
    const float* x      = (const float*)d_in[0];
    const float* qkv_w  = (const float*)d_in[1];
    const float* proj_w = (const float*)d_in[2];
    const float* proj_b = (const float*)d_in[3];
    const float* alpha  = (const float*)d_in[4];
    const float* beta   = (const float*)d_in[5];
    const float* gamma  = (const float*)d_in[6];
    const float* ln1_w  = (const float*)d_in[7];
    const float* ln1_b  = (const float*)d_in[8];
    const float* ln2_w  = (const float*)d_in[9];
    const float* ln2_b  = (const float*)d_in[10];
    const float* w1     = (const float*)d_in[11];
    const float* b1     = (const float*)d_in[12];
    const float* w2     = (const float*)d_in[13];
    const float* b2     = (const float*)d_in[14];
    float* out = (float*)d_out;           // fp32 output; also doubles as x1 buffer

    char* base = (char*)d_ws;
    bf16* wq_bf = (bf16*)base;                 // 1152x384
    bf16* wp_bf = wq_bf + 442368;              // 384x384
    bf16* w1_bf = wq_bf + 589824;              // 1536x384
    bf16* w2_bf = wq_bf + 1179648;             // 384x1536
    bf16* h      = (bf16*)(base + 3538944);
    bf16* qkv    = (bf16*)(base + 9830400);
    bf16* attn_o = (bf16*)(base + 28704768);
    bf16* m      = qkv;                        // overlays qkv+attn_o (both dead by mlp1)
    bf16* Pp     = (bf16*)(base + 34996224);   // 2*TC (proj split-K partials)
    bf16* Pm     = (bf16*)(base + 34996224);   // 4*TC (mlp2 split-K partials; Pp dead)

    cvt_all<<<1728, 256, 0, stream>>>(qkv_w, proj_w, w1, w2, wq_bf);
    ln_kernel<<<T_TOK/4, 256, 0, stream>>>(x, ln1_w, ln1_b, h);
    gemm_bt<EPI_QKV, 384, 1, bf16><<<dim3(9, 64, 1), 256, 0, stream>>>(
        h, wq_bf, nullptr, qkv, T_TOK, 1152);
    attn_kernel<<<768, 256, 0, stream>>>(
        qkv, qkv + TC, qkv + 2*TC, alpha, beta, gamma, attn_o);
    gemm_bt<EPI_NONE, 384, 2, bf16><<<dim3(3, 64, 2), 256, 0, stream>>>(
        attn_o, wp_bf, nullptr, Pp, T_TOK, DIMC);
    ln2_fused<<<T_TOK/4, 256, 0, stream>>>(x, Pp, Pp + TC, proj_b, ln2_w, ln2_b, out, h);
    gemm_bt<EPI_GELU, 384, 1, bf16><<<dim3(12, 64, 1), 256, 0, stream>>>(
        h, w1_bf, b1, m, T_TOK, MLPD);
    gemm_bt<EPI_NONE, 1536, 4, bf16><<<dim3(3, 64, 4), 256, 0, stream>>>(
        m, w2_bf, nullptr, Pm, T_TOK, DIMC);
    reduce4<<<TC/4/256, 256, 0, stream>>>(out, Pm, Pm + TC, Pm + 2*TC, Pm + 3*TC, b2);
}

// Round 10
// 244.785 us; speedup vs baseline: 1.0622x; 1.0048x over previous
//
#include <hip/hip_runtime.h>
#include <hip/hip_bf16.h>
#include <math.h>

#define DIMC 384
#define NH 6
#define HD 64
#define MLPD 1536
#define BS 8
#define SEQ 1024
#define T_TOK (BS*SEQ)                  // 8192 tokens
#define TC ((size_t)T_TOK*DIMC)         // 3,145,728 elems
#define QK_SCALE 0.125f                 // 64^-0.5

typedef __bf16 bf16;
typedef bf16 bf16x4 __attribute__((ext_vector_type(4)));
typedef bf16 bf16x8 __attribute__((ext_vector_type(8)));
typedef float floatx4 __attribute__((ext_vector_type(4)));

// async global->LDS 16B (per-lane LDS dest must equal wave-uniform-base + lane*16)
__device__ __forceinline__ void async_cp16(const void* gsrc, void* ldst) {
    __builtin_amdgcn_global_load_lds(
        (const __attribute__((address_space(1))) unsigned int*)gsrc,
        (__attribute__((address_space(3))) unsigned int*)ldst,
        16, 0, 0);
}

// ---------- fp32 -> bf16 weight conversion (qkv_w | proj_w | w1 | w2 contiguous) ----------
__global__ __launch_bounds__(256)
void cvt_all(const float* __restrict__ s0, const float* __restrict__ s1,
             const float* __restrict__ s2, const float* __restrict__ s3,
             bf16* __restrict__ dst) {
    int i = blockIdx.x * 256 + threadIdx.x;   // i < 442368 float4 chunks
    const int n0 = 110592, n1 = 36864, n2 = 147456;   // float4 counts
    const float4* src; int j;
    if (i < n0)           { src = (const float4*)s0; j = i; }
    else if (i < n0+n1)   { src = (const float4*)s1; j = i - n0; }
    else if (i < n0+n1+n2){ src = (const float4*)s2; j = i - n0 - n1; }
    else                  { src = (const float4*)s3; j = i - n0 - n1 - n2; }
    float4 v = src[j];
    bf16x4 o; o[0] = (bf16)v.x; o[1] = (bf16)v.y; o[2] = (bf16)v.z; o[3] = (bf16)v.w;
    ((bf16x4*)dst)[i] = o;
}

// ---------------- LayerNorm: 256 thr = 4 rows (1 wave/row), fp32 in, bf16 out ----------
__global__ __launch_bounds__(256)
void ln_kernel(const float* __restrict__ x, const float* __restrict__ w,
               const float* __restrict__ b, bf16* __restrict__ out) {
    int row = blockIdx.x * 4 + (threadIdx.x >> 6);
    int t = threadIdx.x & 63;
    const float* xr = x + (size_t)row * DIMC;
    float vals[6];
    float s = 0.f;
    #pragma unroll
    for (int i = 0; i < 6; i++) { vals[i] = xr[t + i*64]; s += vals[i]; }
    #pragma unroll
    for (int m = 32; m; m >>= 1) s += __shfl_xor(s, m);
    float mean = s * (1.0f / DIMC);
    float sq = 0.f;
    #pragma unroll
    for (int i = 0; i < 6; i++) { float d = vals[i] - mean; sq += d * d; }
    #pragma unroll
    for (int m = 32; m; m >>= 1) sq += __shfl_xor(sq, m);
    float rstd = rsqrtf(sq * (1.0f / DIMC) + 1e-5f);
    bf16* orow = out + (size_t)row * DIMC;
    #pragma unroll
    for (int i = 0; i < 6; i++) {
        int c = t + i*64;
        orow[c] = (bf16)((vals[i] - mean) * rstd * w[c] + b[c]);
    }
}

// ---- fused: x1 = x + Pp0 + Pp1 + proj_b (write fp32 x1) ; h = LN2(x1) (write bf16) ----
__global__ __launch_bounds__(256)
void ln2_fused(const float* __restrict__ x, const bf16* __restrict__ p0,
               const bf16* __restrict__ p1, const float* __restrict__ pb,
               const float* __restrict__ w, const float* __restrict__ b,
               float* __restrict__ x1, bf16* __restrict__ h) {
    int row = blockIdx.x * 4 + (threadIdx.x >> 6);
    int t = threadIdx.x & 63;
    size_t base = (size_t)row * DIMC;
    float vals[6];
    float s = 0.f;
    #pragma unroll
    for (int i = 0; i < 6; i++) {
        int c = t + i*64;
        float v = x[base + c] + (float)p0[base + c] + (float)p1[base + c] + pb[c];
        vals[i] = v; s += v;
    }
    #pragma unroll
    for (int m = 32; m; m >>= 1) s += __shfl_xor(s, m);
    float mean = s * (1.0f / DIMC);
    float sq = 0.f;
    #pragma unroll
    for (int i = 0; i < 6; i++) { float d = vals[i] - mean; sq += d * d; }
    #pragma unroll
    for (int m = 32; m; m >>= 1) sq += __shfl_xor(sq, m);
    float rstd = rsqrtf(sq * (1.0f / DIMC) + 1e-5f);
    #pragma unroll
    for (int i = 0; i < 6; i++) {
        int c = t + i*64;
        x1[base + c] = vals[i];
        h[base + c] = (bf16)((vals[i] - mean) * rstd * w[c] + b[c]);
    }
}

// ---- final: out = x1 + b2 + Pm0+Pm1+Pm2+Pm3 (bf16 partials), float4-vectorized ----
__global__ __launch_bounds__(256)
void reduce4(float* __restrict__ xo, const bf16* __restrict__ p0, const bf16* __restrict__ p1,
             const bf16* __restrict__ p2, const bf16* __restrict__ p3,
             const float* __restrict__ b2) {
    int i = blockIdx.x * 256 + threadIdx.x;   // float4 index, < TC/4
    float4 v = ((const float4*)xo)[i];
    int c = (i % 96) * 4;
    float4 bb = *(const float4*)(b2 + c);
    bf16x4 a0 = ((const bf16x4*)p0)[i], a1 = ((const bf16x4*)p1)[i];
    bf16x4 a2 = ((const bf16x4*)p2)[i], a3 = ((const bf16x4*)p3)[i];
    v.x += bb.x + (float)a0[0] + (float)a1[0] + (float)a2[0] + (float)a3[0];
    v.y += bb.y + (float)a0[1] + (float)a1[1] + (float)a2[1] + (float)a3[1];
    v.z += bb.z + (float)a0[2] + (float)a1[2] + (float)a2[2] + (float)a3[2];
    v.w += bb.w + (float)a0[3] + (float)a1[3] + (float)a2[3] + (float)a3[3];
    ((float4*)xo)[i] = v;
}

// ---------------- GEMM: C[M,N] = A[M,K] @ W[N,K]^T, BK=64 single-buffer staging ----------
// block = 4 waves (2x2), tile 128x128, BK=64 (halves barrier count vs BK=32, doubles
// MFMA per stage). LDS stores the 128x64 tile as TWO [128][32] half-tiles (keeps the
// proven 64B row stride + lane-contiguous DMA mapping). 32 KB LDS total, single-buffered
// (dbuf measured neutral r5-vs-r9).
enum { EPI_NONE = 0, EPI_QKV = 1, EPI_GELU = 3 };

template<int EPI, int K, int KS, typename OutT>
__global__ __launch_bounds__(256)
void gemm_bt(const bf16* __restrict__ A, const bf16* __restrict__ W,
             const float* __restrict__ bias, OutT* out, int M, int N) {
    __shared__ __align__(16) bf16 Ash[2*128*32];   // [half][row][32]
    __shared__ __align__(16) bf16 Bsh[2*128*32];
    constexpr int KB = K / KS;               // K extent per block
    constexpr int NI = KB / 64;              // barrier iterations
    int tid = threadIdx.x;
    int lane = tid & 63, w = tid >> 6;
    int quad = lane >> 4, l16 = lane & 15;
    int rbase = blockIdx.y * 128 + (w >> 1) * 64;
    int cbase = blockIdx.x * 128 + (w & 1) * 64;
    int kbase = blockIdx.z * KB;
    // chunk c0 = w*64 + lane in [0,256); thread stages chunks c0 + j*256, j=0..3:
    //   c = c0 + j*256 -> half = j>>1, row = (c0>>2) + (j&1)*64, colchunk = c0&3
    int c0 = w * 64 + lane;
    int row0 = c0 >> 2, cc0 = (c0 & 3) * 8;
    const bf16* Ag = A + (size_t)(blockIdx.y*128 + row0) * K + kbase + cc0;
    const bf16* Wg = W + (size_t)(blockIdx.x*128 + row0) * K + kbase + cc0;
    bf16* As0 = Ash + c0 * 8;                // j-th chunk lands at + j*2048 elems
    bf16* Bs0 = Bsh + c0 * 8;

    int arow = (w >> 1) * 64;
    int brow = (w & 1) * 64;
    floatx4 acc[4][4] = {};
    #pragma unroll
    for (int kk = 0; kk < NI; kk++) {
        __syncthreads();
        #pragma unroll
        for (int j = 0; j < 4; j++) {
            size_t goff = (size_t)(j & 1) * 64 * K + (j >> 1) * 32 + kk * 64;
            async_cp16(Ag + goff, As0 + j * 2048);
            async_cp16(Wg + goff, Bs0 + j * 2048);
        }
        __syncthreads();
        #pragma unroll
        for (int ks2 = 0; ks2 < 2; ks2++) {
            bf16x8 a[4], bfr[4];
            #pragma unroll
            for (int tm = 0; tm < 4; tm++)
                a[tm] = *(const bf16x8*)&Ash[ks2*4096 + (arow + tm*16 + l16) * 32 + quad*8];
            #pragma unroll
            for (int tn = 0; tn < 4; tn++)
                bfr[tn] = *(const bf16x8*)&Bsh[ks2*4096 + (brow + tn*16 + l16) * 32 + quad*8];
            #pragma unroll
            for (int tm = 0; tm < 4; tm++)
                #pragma unroll
                for (int tn = 0; tn < 4; tn++)
                    acc[tm][tn] = __builtin_amdgcn_mfma_f32_16x16x32_bf16(a[tm], bfr[tn], acc[tm][tn], 0, 0, 0);
        }
    }

    #pragma unroll
    for (int tm = 0; tm < 4; tm++)
        #pragma unroll
        for (int tn = 0; tn < 4; tn++) {
            if constexpr (EPI == EPI_QKV) {
                int colb = cbase + tn*16 + l16;       // uniform 'which' per tile (384%16==0)
                int which = colb / 384;
                int rowb = rbase + tm*16 + quad*4;
                int bb = rowb >> 10;
                if (which == 2) {
                    int rem = colb - 768;
                    int hh = rem >> 6, d = rem & 63;
                    int n = rowb & 1023;
                    bf16x4 pk;
                    #pragma unroll
                    for (int r = 0; r < 4; r++) pk[r] = (bf16)acc[tm][tn][r];
                    *(bf16x4*)((bf16*)out + 2*TC + (((size_t)(bb*NH + hh) * HD + d) << 10) + n) = pk;
                } else {
                    int rem = colb - which*384;
                    int hh = rem >> 6, d = rem & 63;
                    #pragma unroll
                    for (int r = 0; r < 4; r++) {
                        int n = (rowb & 1023) + r;
                        ((bf16*)out)[(size_t)which*TC + (((size_t)(bb*NH + hh) * SEQ + n) << 6) + d]
                            = (bf16)acc[tm][tn][r];
                    }
                }
            } else if constexpr (EPI == EPI_NONE) {
                OutT* ob = out + (size_t)blockIdx.z * M * N;
                #pragma unroll
                for (int r = 0; r < 4; r++) {
                    int row = rbase + tm*16 + quad*4 + r;
                    int col = cbase + tn*16 + l16;
                    ob[(size_t)row * N + col] = (OutT)acc[tm][tn][r];
                }
            } else {  // EPI_GELU
                #pragma unroll
                for (int r = 0; r < 4; r++) {
                    int row = rbase + tm*16 + quad*4 + r;
                    int col = cbase + tn*16 + l16;
                    float v = acc[tm][tn][r] + bias[col];
                    v = 0.5f * v * (1.0f + erff(v * 0.70710678118f));
                    out[(size_t)row * N + col] = (OutT)v;
                }
            }
        }
}

// ---------------- Fused L2Q attention, split-K across 4 waves (r5 verbatim) ----------
// 1-D grid of 768 blocks with XCD-aware decode: xcd = L&7 (round-robin dispatch),
// all 16 q-tiles of a head land on the same XCD -> per-XCD K/V working set 1.5 MB < 4 MB L2.
// Known plateau ~58.6 us; r6 (small tiles) and r8 (hoist+reg cap) both regressed it.
__global__ __launch_bounds__(256)
void attn_kernel(const bf16* __restrict__ q, const bf16* __restrict__ k,
                 const bf16* __restrict__ vt, const float* __restrict__ alpha,
                 const float* __restrict__ beta, const float* __restrict__ gamma,
                 bf16* __restrict__ attn_out) {
    __shared__ __align__(16) char smem[52992];
    bf16  (*Psh)[72] = (bf16(*)[72])smem;       // [4*64][72] wave-private P tiles
    float (*Ored)[68] = (float(*)[68])smem;     // [3*64][68] overlay (after loop)
    float* rsred = (float*)(smem + 52224);      // [3*64]

    int L = blockIdx.x;
    int xcd = L & 7, slot = L >> 3;
    int qt = slot & 15;
    int bh = xcd + ((slot >> 4) << 3);          // {xcd, xcd+8, ..., xcd+40}
    int bb = bh / NH, h = bh % NH;
    int q0 = qt * 64;
    int tid = threadIdx.x;
    int w = tid >> 6, lane = tid & 63, quad = lane >> 4, l16 = lane & 15;
    float av = alpha[h] * (QK_SCALE * QK_SCALE), bv = beta[h] * QK_SCALE, gv = gamma[h];
    const bf16* qb  = q  + (size_t)bh * SEQ * HD;
    const bf16* kb  = k  + (size_t)bh * SEQ * HD;
    const bf16* vtb = vt + (size_t)bh * HD * SEQ;

    bf16x8 qa[4][2];
    #pragma unroll
    for (int tm = 0; tm < 4; tm++)
        #pragma unroll
        for (int ks = 0; ks < 2; ks++)
            qa[tm][ks] = *(const bf16x8*)(qb + (size_t)(q0 + tm*16 + l16) * HD + ks*32 + quad*8);

    bf16x8 vone;
    #pragma unroll
    for (int j = 0; j < 8; j++) vone[j] = (bf16)1.0f;

    floatx4 o[4][4] = {};
    floatx4 rsacc[4] = {};
    int prow = w * 64;
    int rd_sw = ((l16 >> 2) & 3) << 3;

    for (int kt = w*4; kt < w*4 + 4; kt++) {
        int kb0 = kt * 64;
        bf16x8 kf[2][4];
        #pragma unroll
        for (int ks = 0; ks < 2; ks++)
            #pragma unroll
            for (int tn = 0; tn < 4; tn++)
                kf[ks][tn] = *(const bf16x8*)(kb + (size_t)(kb0 + tn*16 + l16) * HD + ks*32 + quad*8);
        #pragma unroll
        for (int tm = 0; tm < 4; tm++) {
            floatx4 s[4] = {};
            #pragma unroll
            for (int ks = 0; ks < 2; ks++)
                #pragma unroll
                for (int tn = 0; tn < 4; tn++)
                    s[tn] = __builtin_amdgcn_mfma_f32_16x16x32_bf16(qa[tm][ks], kf[ks][tn], s[tn], 0, 0, 0);
            #pragma unroll
            for (int tn = 0; tn < 4; tn++)
                #pragma unroll
                for (int r = 0; r < 4; r++) {
                    float xx = s[tn][r];
                    float p = fmaxf((av*xx + bv)*xx + gv, 0.f);
                    int row = tm*16 + quad*4 + r;
                    int col = (tn*16 + l16) ^ (quad << 3);   // bank swizzle
                    Psh[prow + row][col] = (bf16)p;
                }
        }
        #pragma unroll
        for (int ks = 0; ks < 2; ks++) {
            bf16x8 vf[4], pf[4];
            #pragma unroll
            for (int tn = 0; tn < 4; tn++)
                vf[tn] = *(const bf16x8*)(vtb + (size_t)(tn*16 + l16) * SEQ + kb0 + ks*32 + quad*8);
            #pragma unroll
            for (int tm = 0; tm < 4; tm++)
                pf[tm] = *(const bf16x8*)&Psh[prow + tm*16 + l16][(ks*32 + quad*8) ^ rd_sw];
            #pragma unroll
            for (int tm = 0; tm < 4; tm++)
                rsacc[tm] = __builtin_amdgcn_mfma_f32_16x16x32_bf16(pf[tm], vone, rsacc[tm], 0, 0, 0);
            #pragma unroll
            for (int tm = 0; tm < 4; tm++)
                #pragma unroll
                for (int tn = 0; tn < 4; tn++)
                    o[tm][tn] = __builtin_amdgcn_mfma_f32_16x16x32_bf16(pf[tm], vf[tn], o[tm][tn], 0, 0, 0);
        }
    }

    __syncthreads();                       // all P reads done -> safe to overlay
    if (w) {
        #pragma unroll
        for (int tm = 0; tm < 4; tm++) {
            #pragma unroll
            for (int tn = 0; tn < 4; tn++)
                #pragma unroll
                for (int r = 0; r < 4; r++)
                    Ored[(w-1)*64 + tm*16 + quad*4 + r][tn*16 + l16] = o[tm][tn][r];
            if (l16 == 0)
                #pragma unroll
                for (int r = 0; r < 4; r++)
                    rsred[(w-1)*64 + tm*16 + quad*4 + r] = rsacc[tm][r];
        }
    }
    __syncthreads();
    if (w == 0) {
        #pragma unroll
        for (int j = 0; j < 3; j++)
            #pragma unroll
            for (int tm = 0; tm < 4; tm++) {
                #pragma unroll
                for (int tn = 0; tn < 4; tn++)
                    #pragma unroll
                    for (int r = 0; r < 4; r++)
                        o[tm][tn][r] += Ored[j*64 + tm*16 + quad*4 + r][tn*16 + l16];
                #pragma unroll
                for (int r = 0; r < 4; r++)
                    rsacc[tm][r] += rsred[j*64 + tm*16 + quad*4 + r];
            }
        #pragma unroll
        for (int tm = 0; tm < 4; tm++)
            #pragma unroll
            for (int tn = 0; tn < 4; tn++)
                #pragma unroll
                for (int r = 0; r < 4; r++) {
                    int n = q0 + tm*16 + quad*4 + r;
                    attn_out[((size_t)(bb*SEQ + n)) * DIMC + h*HD + tn*16 + l16] =
                        (bf16)(o[tm][tn][r] / (rsacc[tm][r] + 1e-6f));
                }
    }
}

// ---------------- driver ----------------
extern "C" void kernel_launch(void* const* d_in, const int* in_sizes, int n_in,
                              void* d_out, int out_size, void* d_ws, size_t ws_size,
                              hipStream_t stream) {
    const float* x      = (const float*)d_in[0];
    const float* qkv_w  = (const float*)d_in[1];
    const float* proj_w = (const float*)d_in[2];
    const float* proj_b = (const float*)d_in[3];
    const float* alpha  = (const float*)d_in[4];
    const float* beta   = (const float*)d_in[5];
    const float* gamma  = (const float*)d_in[6];
    const float* ln1_w  = (const float*)d_in[7];
    const float* ln1_b  = (const float*)d_in[8];
    const float* ln2_w  = (const float*)d_in[9];
    const float* ln2_b  = (const float*)d_in[10];
    const float* w1     = (const float*)d_in[11];
    const float* b1     = (const float*)d_in[12];
    const float* w2     = (const float*)d_in[13];
    const float* b2     = (const float*)d_in[14];
    float* out = (float*)d_out;           // fp32 output; also doubles as x1 buffer

    char* base = (char*)d_ws;
    bf16* wq_bf = (bf16*)base;                 // 1152x384
    bf16* wp_bf = wq_bf + 442368;              // 384x384
    bf16* w1_bf = wq_bf + 589824;              // 1536x384
    bf16* w2_bf = wq_bf + 1179648;             // 384x1536
    bf16* h      = (bf16*)(base + 3538944);
    bf16* qkv    = (bf16*)(base + 9830400);
    bf16* attn_o = (bf16*)(base + 28704768);
    bf16* m      = qkv;                        // overlays qkv+attn_o (both dead by mlp1)
    bf16* Pp     = (bf16*)(base + 34996224);   // 2*TC (proj split-K partials)
    bf16* Pm     = (bf16*)(base + 34996224);   // 4*TC (mlp2 split-K partials; Pp dead)

    cvt_all<<<1728, 256, 0, stream>>>(qkv_w, proj_w, w1, w2, wq_bf);
    ln_kernel<<<T_TOK/4, 256, 0, stream>>>(x, ln1_w, ln1_b, h);
    gemm_bt<EPI_QKV, 384, 1, bf16><<<dim3(9, 64, 1), 256, 0, stream>>>(
        h, wq_bf, nullptr, qkv, T_TOK, 1152);
    attn_kernel<<<768, 256, 0, stream>>>(
        qkv, qkv + TC, qkv + 2*TC, alpha, beta, gamma, attn_o);
    gemm_bt<EPI_NONE, 384, 2, bf16><<<dim3(3, 64, 2), 256, 0, stream>>>(
        attn_o, wp_bf, nullptr, Pp, T_TOK, DIMC);
    ln2_fused<<<T_TOK/4, 256, 0, stream>>>(x, Pp, Pp + TC, proj_b, ln2_w, ln2_b, out, h);
    gemm_bt<EPI_GELU, 384, 1, bf16><<<dim3(12, 64, 1), 256, 0, stream>>>(
        h, w1_bf, b1, m, T_TOK, MLPD);
    gemm_bt<EPI_NONE, 1536, 4, bf16><<<dim3(3, 64, 4), 256, 0, stream>>>(
        m, w2_bf, nullptr, Pm, T_TOK, DIMC);
    reduce4<<<TC/4/256, 256, 0, stream>>>(out, Pm, Pm + TC, Pm + 2*TC, Pm + 3*TC, b2);
}